// Round 1
// baseline (220.837 us; speedup 1.0000x reference)
//
#include <hip/hip_runtime.h>

#define MARGIN 0.2f
#define LAMBDA_CONSISTENCY 0.1f
#define COS_EPS 1e-8f

// ---------------------------------------------------------------------------
// Kernel 1: column pass.
// Streams S row-by-row through LDS. Each block owns a contiguous chunk of
// rows; threads own 8 columns each (B=8192, 1024 threads). For each staged
// row k: dot_col[i] += S[k,i]*S[k,ht[i]] (LDS gather), colsq[i] += S[k,i]^2.
// Partials combined across blocks with atomicAdd (256 adders per address).
// ---------------------------------------------------------------------------
__global__ __launch_bounds__(1024) void col_pass_kernel(
    const float* __restrict__ S, const int* __restrict__ ht,
    float* __restrict__ dot_col, float* __restrict__ colsq,
    int B, int rows_per_block) {
  extern __shared__ float lds[];  // B floats = 32 KB for B=8192
  const int t = threadIdx.x;

  float dacc[8], sacc[8];
  int coli[8], hti[8];
#pragma unroll
  for (int c = 0; c < 8; ++c) {
    dacc[c] = 0.f;
    sacc[c] = 0.f;
    coli[c] = t + 1024 * c;
    hti[c] = ht[coli[c]];
  }

  const int k0 = blockIdx.x * rows_per_block;
  float4* lds4 = (float4*)lds;

  for (int k = k0; k < k0 + rows_per_block; ++k) {
    const float4* row4 = (const float4*)(S + (size_t)k * B);
    // 8192 floats = 2048 float4; 1024 threads x 2 coalesced float4 loads
#pragma unroll
    for (int q = 0; q < 2; ++q) lds4[t + 1024 * q] = row4[t + 1024 * q];
    __syncthreads();
#pragma unroll
    for (int c = 0; c < 8; ++c) {
      float v = lds[coli[c]];   // stride-1 across lanes: conflict-free
      float g = lds[hti[c]];    // random gather within row
      dacc[c] += v * g;
      sacc[c] += v * v;
    }
    __syncthreads();
  }

#pragma unroll
  for (int c = 0; c < 8; ++c) {
    atomicAdd(&dot_col[coli[c]], dacc[c]);
    atomicAdd(&colsq[coli[c]], sacc[c]);
  }
}

// ---------------------------------------------------------------------------
// Kernel 2: row pass. One block per row i: reads rows i and ha[i] coalesced,
// computes dot(row_i, row_ha) and ||row_i||^2, block-reduces, writes once.
// ---------------------------------------------------------------------------
__global__ __launch_bounds__(256) void row_pass_kernel(
    const float* __restrict__ S, const int* __restrict__ ha,
    float* __restrict__ dot_row, float* __restrict__ rowsq, int B) {
  __shared__ float red[8];
  const int i = blockIdx.x;
  const int t = threadIdx.x;
  const float4* ri = (const float4*)(S + (size_t)i * B);
  const float4* ra = (const float4*)(S + (size_t)ha[i] * B);

  float d = 0.f, s = 0.f;
#pragma unroll
  for (int q = 0; q < 8; ++q) {  // 2048 float4 / 256 threads = 8
    float4 a = ri[t + 256 * q];
    float4 b = ra[t + 256 * q];
    d += a.x * b.x + a.y * b.y + a.z * b.z + a.w * b.w;
    s += a.x * a.x + a.y * a.y + a.z * a.z + a.w * a.w;
  }
#pragma unroll
  for (int o = 32; o > 0; o >>= 1) {
    d += __shfl_down(d, o, 64);
    s += __shfl_down(s, o, 64);
  }
  const int wid = t >> 6, lane = t & 63;
  if (lane == 0) { red[wid] = d; red[4 + wid] = s; }
  __syncthreads();
  if (t == 0) {
    dot_row[i] = red[0] + red[1] + red[2] + red[3];
    rowsq[i]  = red[4] + red[5] + red[6] + red[7];
  }
}

// ---------------------------------------------------------------------------
// Kernel 3: finalize. Single block; gathers the 3 scalar S elements per i,
// assembles triplet + consistency terms, block-reduces to the 3 outputs.
// ---------------------------------------------------------------------------
__global__ __launch_bounds__(1024) void finalize_kernel(
    const float* __restrict__ S, const unsigned char* __restrict__ pmask,
    const int* __restrict__ ha, const int* __restrict__ ht,
    const float* __restrict__ dot_col, const float* __restrict__ colsq,
    const float* __restrict__ dot_row, const float* __restrict__ rowsq,
    float* __restrict__ out, int B) {
  const int t = threadIdx.x;
  float cnt = 0.f, tripS = 0.f, consS = 0.f;

  for (int i = t; i < B; i += 1024) {
    const float m = pmask[(size_t)i * B + i] ? 1.f : 0.f;
    const int a = ha[i];
    const int x = ht[i];
    const float pos = S[(size_t)i * B + i];
    const float an  = S[(size_t)a * B + i];
    const float tn  = S[(size_t)i * B + x];
    const float trip = fmaxf(MARGIN - pos + tn, 0.f) + fmaxf(MARGIN - pos + an, 0.f);

    const float cosA = dot_row[i] / fmaxf(sqrtf(rowsq[i]) * sqrtf(rowsq[a]), COS_EPS);
    const float cosT = dot_col[i] / fmaxf(sqrtf(colsq[i]) * sqrtf(colsq[x]), COS_EPS);
    const float cons = fmaxf(fabsf(cosA - cosT), 0.f);  // SIGMA_MARGIN = 0

    cnt += m;
    tripS += trip * m;
    consS += cons * m;
  }

  __shared__ float red[48];
#pragma unroll
  for (int o = 32; o > 0; o >>= 1) {
    cnt   += __shfl_down(cnt, o, 64);
    tripS += __shfl_down(tripS, o, 64);
    consS += __shfl_down(consS, o, 64);
  }
  const int wid = t >> 6, lane = t & 63;
  if (lane == 0) { red[wid] = cnt; red[16 + wid] = tripS; red[32 + wid] = consS; }
  __syncthreads();
  if (t == 0) {
    float c = 0.f, tp = 0.f, cs = 0.f;
    for (int w = 0; w < 16; ++w) { c += red[w]; tp += red[16 + w]; cs += red[32 + w]; }
    c = fmaxf(c, 1.f);
    const float triplet = tp / c;
    const float consistency = cs / c;
    out[0] = triplet + LAMBDA_CONSISTENCY * consistency;
    out[1] = triplet;
    out[2] = consistency;
  }
}

extern "C" void kernel_launch(void* const* d_in, const int* in_sizes, int n_in,
                              void* d_out, int out_size, void* d_ws, size_t ws_size,
                              hipStream_t stream) {
  const float* S = (const float*)d_in[0];
  const unsigned char* pmask = (const unsigned char*)d_in[1];  // jnp bool -> 1 byte
  const int* ha = (const int*)d_in[2];
  const int* ht = (const int*)d_in[3];
  const int B = in_sizes[2];  // 8192

  float* ws = (float*)d_ws;
  float* dot_col = ws;
  float* colsq   = ws + B;
  float* dot_row = ws + 2 * B;
  float* rowsq   = ws + 3 * B;

  // zero only the atomically-accumulated arrays
  hipMemsetAsync(ws, 0, (size_t)2 * B * sizeof(float), stream);

  const int blocks1 = 256;  // 32 rows per block at B=8192
  col_pass_kernel<<<blocks1, 1024, B * sizeof(float), stream>>>(
      S, ht, dot_col, colsq, B, B / blocks1);

  row_pass_kernel<<<B, 256, 0, stream>>>(S, ha, dot_row, rowsq, B);

  finalize_kernel<<<1, 1024, 0, stream>>>(
      S, pmask, ha, ht, dot_col, colsq, dot_row, rowsq, (float*)d_out, B);
}

// Round 2
// 183.698 us; speedup vs baseline: 1.2022x; 1.2022x over previous
//
#include <hip/hip_runtime.h>

#define MARGIN 0.2f
#define LAMBDA_CONSISTENCY 0.1f
#define COS_EPS 1e-8f

// ---------------------------------------------------------------------------
// Fused pass. Each block owns a contiguous chunk of rows. Per row k:
//   - load row k coalesced into registers, stage into LDS
//   - load row ha[k] coalesced (L3-resident: S fits Infinity Cache)
//   - dot_row[k], rowsq[k] from registers via block reduction
//   - column contributions from the staged LDS row:
//       dot_col[i] += S[k,i]*S[k,ht[i]]   (LDS gather)
//       colsq[i]   += S[k,i]^2
// S is read from HBM exactly once, coalesced.
// ---------------------------------------------------------------------------
__global__ __launch_bounds__(1024) void fused_pass_kernel(
    const float* __restrict__ S, const int* __restrict__ ha,
    const int* __restrict__ ht,
    float* __restrict__ dot_col, float* __restrict__ colsq,
    float* __restrict__ dot_row, float* __restrict__ rowsq,
    int B, int rows_per_block) {
  extern __shared__ float lds[];     // B floats staging + 32 reduction slots
  float* red = lds + B;
  const int t = threadIdx.x;

  float dacc[8], sacc[8];
  int hti[8];
#pragma unroll
  for (int c = 0; c < 8; ++c) {
    dacc[c] = 0.f;
    sacc[c] = 0.f;
    hti[c] = ht[t + 1024 * c];
  }

  const int k0 = blockIdx.x * rows_per_block;
  float4* lds4 = (float4*)lds;

  for (int k = k0; k < k0 + rows_per_block; ++k) {
    const float4* rowk = (const float4*)(S + (size_t)k * B);
    const float4* rowa = (const float4*)(S + (size_t)ha[k] * B);
    // 8192 floats = 2048 float4; 1024 threads x 2 coalesced float4 loads
    float4 a0 = rowk[t], a1 = rowk[t + 1024];
    float4 b0 = rowa[t], b1 = rowa[t + 1024];
    lds4[t] = a0;
    lds4[t + 1024] = a1;

    float d = a0.x * b0.x + a0.y * b0.y + a0.z * b0.z + a0.w * b0.w
            + a1.x * b1.x + a1.y * b1.y + a1.z * b1.z + a1.w * b1.w;
    float s = a0.x * a0.x + a0.y * a0.y + a0.z * a0.z + a0.w * a0.w
            + a1.x * a1.x + a1.y * a1.y + a1.z * a1.z + a1.w * a1.w;
#pragma unroll
    for (int o = 32; o > 0; o >>= 1) {
      d += __shfl_down(d, o, 64);
      s += __shfl_down(s, o, 64);
    }
    if ((t & 63) == 0) { red[t >> 6] = d; red[16 + (t >> 6)] = s; }
    __syncthreads();  // staging + red visible

#pragma unroll
    for (int c = 0; c < 8; ++c) {
      float v = lds[t + 1024 * c];  // stride-1 across lanes: conflict-free
      float g = lds[hti[c]];        // random gather within row (~2-way, free)
      dacc[c] += v * g;
      sacc[c] += v * v;
    }
    if (t == 0) {
      float dd = 0.f, ss = 0.f;
#pragma unroll
      for (int w = 0; w < 16; ++w) { dd += red[w]; ss += red[16 + w]; }
      dot_row[k] = dd;
      rowsq[k] = ss;
    }
    __syncthreads();  // before overwriting the staged row
  }

#pragma unroll
  for (int c = 0; c < 8; ++c) {
    atomicAdd(&dot_col[t + 1024 * c], dacc[c]);
    atomicAdd(&colsq[t + 1024 * c], sacc[c]);
  }
}

// ---------------------------------------------------------------------------
// Finalize: single block; gathers 3 scalar S elements per i, assembles
// triplet + consistency terms, block-reduces to the 3 outputs.
// ---------------------------------------------------------------------------
__global__ __launch_bounds__(1024) void finalize_kernel(
    const float* __restrict__ S, const unsigned char* __restrict__ pmask,
    const int* __restrict__ ha, const int* __restrict__ ht,
    const float* __restrict__ dot_col, const float* __restrict__ colsq,
    const float* __restrict__ dot_row, const float* __restrict__ rowsq,
    float* __restrict__ out, int B) {
  const int t = threadIdx.x;
  float cnt = 0.f, tripS = 0.f, consS = 0.f;

  for (int i = t; i < B; i += 1024) {
    const float m = pmask[(size_t)i * B + i] ? 1.f : 0.f;
    const int a = ha[i];
    const int x = ht[i];
    const float pos = S[(size_t)i * B + i];
    const float an  = S[(size_t)a * B + i];
    const float tn  = S[(size_t)i * B + x];
    const float trip = fmaxf(MARGIN - pos + tn, 0.f) + fmaxf(MARGIN - pos + an, 0.f);

    const float cosA = dot_row[i] / fmaxf(sqrtf(rowsq[i]) * sqrtf(rowsq[a]), COS_EPS);
    const float cosT = dot_col[i] / fmaxf(sqrtf(colsq[i]) * sqrtf(colsq[x]), COS_EPS);
    const float cons = fmaxf(fabsf(cosA - cosT), 0.f);  // SIGMA_MARGIN = 0

    cnt += m;
    tripS += trip * m;
    consS += cons * m;
  }

  __shared__ float red[48];
#pragma unroll
  for (int o = 32; o > 0; o >>= 1) {
    cnt   += __shfl_down(cnt, o, 64);
    tripS += __shfl_down(tripS, o, 64);
    consS += __shfl_down(consS, o, 64);
  }
  const int wid = t >> 6, lane = t & 63;
  if (lane == 0) { red[wid] = cnt; red[16 + wid] = tripS; red[32 + wid] = consS; }
  __syncthreads();
  if (t == 0) {
    float c = 0.f, tp = 0.f, cs = 0.f;
    for (int w = 0; w < 16; ++w) { c += red[w]; tp += red[16 + w]; cs += red[32 + w]; }
    c = fmaxf(c, 1.f);
    const float triplet = tp / c;
    const float consistency = cs / c;
    out[0] = triplet + LAMBDA_CONSISTENCY * consistency;
    out[1] = triplet;
    out[2] = consistency;
  }
}

extern "C" void kernel_launch(void* const* d_in, const int* in_sizes, int n_in,
                              void* d_out, int out_size, void* d_ws, size_t ws_size,
                              hipStream_t stream) {
  const float* S = (const float*)d_in[0];
  const unsigned char* pmask = (const unsigned char*)d_in[1];  // jnp bool -> 1 byte
  const int* ha = (const int*)d_in[2];
  const int* ht = (const int*)d_in[3];
  const int B = in_sizes[2];  // 8192

  float* ws = (float*)d_ws;
  float* dot_col = ws;
  float* colsq   = ws + B;
  float* dot_row = ws + 2 * B;
  float* rowsq   = ws + 3 * B;

  // zero only the atomically-accumulated arrays
  hipMemsetAsync(ws, 0, (size_t)2 * B * sizeof(float), stream);

  const int blocks = 512;  // 16 rows/block at B=8192; 2 blocks/CU
  fused_pass_kernel<<<blocks, 1024, (B + 32) * sizeof(float), stream>>>(
      S, ha, ht, dot_col, colsq, dot_row, rowsq, B, B / blocks);

  finalize_kernel<<<1, 1024, 0, stream>>>(
      S, pmask, ha, ht, dot_col, colsq, dot_row, rowsq, (float*)d_out, B);
}